// Round 3
// baseline (598.531 us; speedup 1.0000x reference)
//
#include <hip/hip_runtime.h>

// NCC loss: five 9x9x9 box sums (I, J, I^2, J^2, I*J), stride 1, pad 4,
// count_include_pad (divisor 729), ncc = cov^2/(varI*varJ+eps), out = -mean.
// Shapes fixed: [2,1,192,192,192] fp32.
//
// R10. R9 POST-MORTEM: WRITE 744MB / FETCH 547MB at 128 VGPR -> still
// spilling ~3KB/thread. Cause: R9's YSTEP declared all 20 LDS loads live
// (50 VGPRs) before the tree consumed them; peak = rings(90)+prefetch(24)
// +50 > 128 -> rings spilled in-loop. NOT the launch bound.
// Fix kept-static, pressure-bounded:
//  (1) YSTEP load->consume: running mid-sum of rows 1..8 (one rr/qq live),
//      then A = mid+row0, B = mid+row9 (also drops R7's subtract).
//      Peak live ~16 regs.
//  (2) LOAD zeroing moved to else-branch (z-edge only, uniform branch);
//      regs zero-initialized once; cv-invalid lanes stay 0 (cv invariant).
//      Saves ~24 v_mov/thread/slice vs R7/R9.
//  (3) kept from R8/R9: 2x18 static-parity loop (PB,K literals -> imm-offset
//      DS), rcp EMIT (|err| ~1e-10), launch_bounds(256,2).
// Carried from R7: lgkmcnt-only slice barrier (global prefetch survives),
// xs1 stride 20 (2-way reads = free), named-scalar z-rings, 16x32 tile,
// 2 y-outs/thread, direct-global float4 x-phase, XCD swizzle.

#define S    192
#define SS   (S * S)
#define TX   16
#define YT   32                  // y-tile; thread (tx,tyt) owns y=2*tyt,2*tyt+1
#define NTHR 256
#define KZ   32
#define RAD  4
#define WIN  9
#define NSL  (KZ + 2 * RAD)      // 40
#define HXR  (YT + 2 * RAD)      // 40 halo rows
#define XSW  17                  // xs4 padded row stride (float4 units)
#define XSW1 20                  // xs1 padded row stride (floats): banks 8t+tx
#define NVOX (2.0 * S * S * S)

// LDS-only barrier: waves' DS ops complete (lgkmcnt) + rendezvous. No vmcnt
// drain -> global prefetch survives the barrier.
#define LDS_BARRIER() __asm__ __volatile__("s_waitcnt lgkmcnt(0)\n\ts_barrier" ::: "memory")

__global__ void ncc_init(double* ws) { ws[0] = 0.0; }

__global__ void ncc_final(const double* __restrict__ ws, float* __restrict__ out) {
    out[0] = (float)(-ws[0] / NVOX);
}

__device__ __forceinline__ float4 f4add(float4 a, float4 b) {
    return make_float4(a.x + b.x, a.y + b.y, a.z + b.z, a.w + b.w);
}
__device__ __forceinline__ float4 f4sub(float4 a, float4 b) {
    return make_float4(a.x - b.x, a.y - b.y, a.z - b.z, a.w - b.w);
}

__global__ __launch_bounds__(NTHR, 2) void ncc_main(const float* __restrict__ I,
                                                    const float* __restrict__ J,
                                                    double* __restrict__ ws) {
    // LDS ~28 KB: xs4 2*40*17*16 + xs1 2*40*20*4 + red
    __shared__ float4 xs4[2][HXR][XSW];    // (sI, sJ, sI2, sJ2)
    __shared__ float  xs1[2][HXR][XSW1];   // sIJ
    __shared__ float  red[4];

    const int tid = threadIdx.x;          // 0..255 (flat)
    const int tx  = tid & 15;
    const int tyt = tid >> 4;             // 0..15 -> outputs y=2*tyt, 2*tyt+1

    // XCD swizzle over 864 blocks: id&7 = XCD owns a 3x3 xy-patch, bijective.
    const int id  = blockIdx.x;           // 0..863
    const int xcd = id & 7;
    const int lo  = id >> 3;              // 0..107
    const int t   = lo % 9;
    const int bzq = lo / 9;               // 0..11
    const int bx  = (xcd & 3) * 3 + t % 3;     // 0..11
    const int by  = (xcd >> 2) * 3 + t / 3;    // 0..5
    const int b   = (bzq >= 6) ? 1 : 0;
    const int zc  = bzq - 6 * b;
    const int x0 = bx * TX, y0 = by * YT, z0 = zc * KZ;

    const float* Ib = I + (size_t)b * S * SS;
    const float* Jb = J + (size_t)b * S * SS;

    // x-tasks: 160 threads, task (row xr 0..39, quad xq 0..3) -> 4 x-outputs
    // from 12 input cols (4-aligned chunks, all-valid or all-invalid).
    const bool xtask = (tid < 4 * HXR);
    const int  xr  = tid >> 2;            // 0..39
    const int  xq  = tid & 3;
    const int  gy  = y0 - RAD + xr;
    const bool gyv = xtask && ((unsigned)gy < (unsigned)S);
    const int  c0  = x0 + 4 * xq - RAD;
    const bool cv0 = gyv && ((unsigned)(c0    ) < (unsigned)S);
    const bool cv1 = gyv && ((unsigned)(c0 + 4) < (unsigned)S);
    const bool cv2 = gyv && ((unsigned)(c0 + 8) < (unsigned)S);
    const ptrdiff_t rowoff = gyv ? ((ptrdiff_t)gy * S + c0) : 0;

    const float4 F40 = make_float4(0.f, 0.f, 0.f, 0.f);
    // Zero-initialized once: cv-invalid lanes stay 0 forever (cv invariant);
    // z-edge slices re-zero via the else branch below.
    float4 li0 = F40, li1 = F40, li2 = F40, lj0 = F40, lj1 = F40, lj2 = F40;

    auto LOAD = [&](int p) {
        const int zi = z0 - RAD + p;
        if (p < NSL && (unsigned)zi < (unsigned)S) {
            const float* rI = Ib + (size_t)zi * SS + rowoff;
            const float* rJ = Jb + (size_t)zi * SS + rowoff;
            if (cv0) { li0 = *(const float4*)(rI);     lj0 = *(const float4*)(rJ); }
            if (cv1) { li1 = *(const float4*)(rI + 4); lj1 = *(const float4*)(rJ + 4); }
            if (cv2) { li2 = *(const float4*)(rI + 8); lj2 = *(const float4*)(rJ + 8); }
        } else {
            // Rare (z-edge / past-end) uniform path only.
            li0 = li1 = li2 = lj0 = lj1 = lj2 = F40;
        }
    };

    // x-phase: CB is a COMPILE-TIME literal -> all writes are immediate-offset
    // ds_write off one hoisted base.
#define XPHASE(CB) do {                                                     \
        if (xtask) {                                                        \
            const float iv[12] = { li0.x, li0.y, li0.z, li0.w,              \
                                   li1.x, li1.y, li1.z, li1.w,              \
                                   li2.x, li2.y, li2.z, li2.w };            \
            const float jv[12] = { lj0.x, lj0.y, lj0.z, lj0.w,              \
                                   lj1.x, lj1.y, lj1.z, lj1.w,              \
                                   lj2.x, lj2.y, lj2.z, lj2.w };            \
            float a = 0.f, bb = 0.f, c = 0.f, d = 0.f, e = 0.f;             \
            _Pragma("unroll")                                               \
            for (int m = 0; m < WIN; ++m) {                                 \
                a += iv[m];                                                 \
                bb += jv[m];                                                \
                c = fmaf(iv[m], iv[m], c);                                  \
                d = fmaf(jv[m], jv[m], d);                                  \
                e = fmaf(iv[m], jv[m], e);                                  \
            }                                                               \
            _Pragma("unroll")                                               \
            for (int k = 0; k < 4; ++k) {                                   \
                if (k > 0) {                                                \
                    a += iv[8 + k] - iv[k - 1];                             \
                    bb += jv[8 + k] - jv[k - 1];                            \
                    c += fmaf(iv[8 + k], iv[8 + k], -iv[k - 1] * iv[k - 1]);\
                    d += fmaf(jv[8 + k], jv[8 + k], -jv[k - 1] * jv[k - 1]);\
                    e += fmaf(iv[8 + k], jv[8 + k], -iv[k - 1] * jv[k - 1]);\
                }                                                           \
                xs4[CB][xr][4 * xq + k] = make_float4(a, bb, c, d);         \
                xs1[CB][xr][4 * xq + k] = e;                                \
            }                                                               \
        }                                                                   \
    } while (0)

    // z-rings as NAMED scalars (no arrays -> no scratch demotion possible).
    float4 a4_0 = F40, a4_1 = F40, a4_2 = F40, a4_3 = F40, a4_4 = F40,
           a4_5 = F40, a4_6 = F40, a4_7 = F40, a4_8 = F40;
    float  a1_0 = 0.f, a1_1 = 0.f, a1_2 = 0.f, a1_3 = 0.f, a1_4 = 0.f,
           a1_5 = 0.f, a1_6 = 0.f, a1_7 = 0.f, a1_8 = 0.f;
    float4 b4_0 = F40, b4_1 = F40, b4_2 = F40, b4_3 = F40, b4_4 = F40,
           b4_5 = F40, b4_6 = F40, b4_7 = F40, b4_8 = F40;
    float  b1_0 = 0.f, b1_1 = 0.f, b1_2 = 0.f, b1_3 = 0.f, b1_4 = 0.f,
           b1_5 = 0.f, b1_6 = 0.f, b1_7 = 0.f, b1_8 = 0.f;
    float4 runA4 = F40, runB4 = F40;
    float  runA1 = 0.f, runB1 = 0.f;
    float  acc = 0.f;
    const int yA = 2 * tyt;               // taps yA..yA+9 cover both outputs

    // One-instruction reciprocal (v_rcp_f32, ~1 ulp): final |err| ~1e-10 abs.
#define EMIT(R4, R1) do {                                                   \
        const float inv_ = 1.0f / 729.0f;                                   \
        const float mI_ = (R4).x * inv_, mJ_ = (R4).y * inv_;               \
        const float vI_ = (R4).z * inv_ - mI_ * mI_;                        \
        const float vJ_ = (R4).w * inv_ - mJ_ * mJ_;                        \
        const float cIJ_ = (R1) * inv_ - mI_ * mJ_;                         \
        acc = fmaf(cIJ_ * cIJ_,                                             \
                   __builtin_amdgcn_rcpf(vI_ * vJ_ + 1e-5f), acc);          \
    } while (0)

    // y-phase, STATIC buffer parity PB and ring slot K. Load->consume:
    // running mid-sum of rows 1..8 keeps ONE incoming rr/qq live (peak ~16
    // regs vs R9's 50 -> no ring spill). A = mid+row0, B = mid+row9.
#define YSTEP(PB, K, DOEMIT) do {                                           \
        const float4 t0 = xs4[PB][yA + 0][tx];                              \
        const float  u0 = xs1[PB][yA + 0][tx];                              \
        float4 m4 = xs4[PB][yA + 1][tx];                                    \
        float  m1 = xs1[PB][yA + 1][tx];                                    \
        float4 rr; float qq;                                                \
        rr = xs4[PB][yA + 2][tx]; qq = xs1[PB][yA + 2][tx];                 \
        m4 = f4add(m4, rr); m1 += qq;                                       \
        rr = xs4[PB][yA + 3][tx]; qq = xs1[PB][yA + 3][tx];                 \
        m4 = f4add(m4, rr); m1 += qq;                                       \
        rr = xs4[PB][yA + 4][tx]; qq = xs1[PB][yA + 4][tx];                 \
        m4 = f4add(m4, rr); m1 += qq;                                       \
        rr = xs4[PB][yA + 5][tx]; qq = xs1[PB][yA + 5][tx];                 \
        m4 = f4add(m4, rr); m1 += qq;                                       \
        rr = xs4[PB][yA + 6][tx]; qq = xs1[PB][yA + 6][tx];                 \
        m4 = f4add(m4, rr); m1 += qq;                                       \
        rr = xs4[PB][yA + 7][tx]; qq = xs1[PB][yA + 7][tx];                 \
        m4 = f4add(m4, rr); m1 += qq;                                       \
        rr = xs4[PB][yA + 8][tx]; qq = xs1[PB][yA + 8][tx];                 \
        m4 = f4add(m4, rr); m1 += qq;                                       \
        rr = xs4[PB][yA + 9][tx]; qq = xs1[PB][yA + 9][tx];                 \
        const float4 sA4 = f4add(m4, t0);  const float sA1 = m1 + u0;       \
        const float4 sB4 = f4add(m4, rr);  const float sB1 = m1 + qq;       \
        runA4 = f4add(runA4, f4sub(sA4, a4_##K));  a4_##K = sA4;            \
        runA1 += sA1 - a1_##K;                     a1_##K = sA1;            \
        runB4 = f4add(runB4, f4sub(sB4, b4_##K));  b4_##K = sB4;            \
        runB1 += sB1 - b1_##K;                     b1_##K = sB1;            \
        if (DOEMIT) { EMIT(runA4, runA1); EMIT(runB4, runB1); }             \
    } while (0)

    // BODY position p = idx-1: y(p) | x(p+1) | load(p+2) | lds-barrier.
    // PB = p&1 and K = p%9 are literals per position.
#define BODY(PB, K, DOEMIT) do {                                            \
        YSTEP(PB, K, DOEMIT);                                               \
        XPHASE((PB) ^ 1);                                                   \
        LOAD(idx + 1);                                                      \
        LDS_BARRIER();                                                      \
        ++idx;                                                              \
    } while (0)

    // Pipeline prologue.
    LOAD(0);
    XPHASE(0);
    LOAD(1);
    LDS_BARRIER();

    // Main loop: 2 groups of 18 BODYs (18 = 0 mod 2 and mod 9 -> parity and
    // ring slot are static per position; group g covers p = 18g .. 18g+17).
    // Emit starts at p = 2*RAD = 8: static true for pos 8..17, uniform
    // scalar bool (g != 0) for pos 0..7.
    int idx = 1;
    #pragma unroll 1
    for (int g = 0; g < 2; ++g) {
        const bool em = (g != 0);
        BODY(0, 0, em);   BODY(1, 1, em);   BODY(0, 2, em);   BODY(1, 3, em);
        BODY(0, 4, em);   BODY(1, 5, em);   BODY(0, 6, em);   BODY(1, 7, em);
        BODY(0, 8, true); BODY(1, 0, true); BODY(0, 1, true); BODY(1, 2, true);
        BODY(0, 3, true); BODY(1, 4, true); BODY(0, 5, true); BODY(1, 6, true);
        BODY(0, 7, true); BODY(1, 8, true);
    }
    // Tail: p = 36, 37, 38, then final y-only step p = 39 (39%9 = 3, odd).
    BODY(0, 0, true);
    BODY(1, 1, true);
    BODY(0, 2, true);
    YSTEP(1, 3, true);
#undef BODY
#undef YSTEP
#undef EMIT
#undef XPHASE

    // Block reduction: wave shuffle -> LDS -> one double atomic.
    // (Full __syncthreads here is fine: once per block, nothing to prefetch.)
    float v = acc;
    #pragma unroll
    for (int off = 32; off >= 1; off >>= 1)
        v += __shfl_down(v, off, 64);
    const int lane = tid & 63;
    const int wid  = tid >> 6;
    if (lane == 0) red[wid] = v;
    __syncthreads();
    if (tid == 0) {
        atomicAdd(ws, (double)(red[0] + red[1] + red[2] + red[3]));
    }
}

extern "C" void kernel_launch(void* const* d_in, const int* in_sizes, int n_in,
                              void* d_out, int out_size, void* d_ws, size_t ws_size,
                              hipStream_t stream) {
    const float* I = (const float*)d_in[0];   // y_pred
    const float* J = (const float*)d_in[1];   // y_true
    double* ws = (double*)d_ws;
    float* out = (float*)d_out;

    hipLaunchKernelGGL(ncc_init, dim3(1), dim3(1), 0, stream, ws);

    hipLaunchKernelGGL(ncc_main, dim3(12 * 6 * 12), dim3(NTHR), 0, stream,
                       I, J, ws);

    hipLaunchKernelGGL(ncc_final, dim3(1), dim3(1), 0, stream, ws, out);
}

// Round 5
// 235.340 us; speedup vs baseline: 2.5433x; 2.5433x over previous
//
#include <hip/hip_runtime.h>

// NCC loss: five 9x9x9 box sums (I, J, I^2, J^2, I*J), stride 1, pad 4,
// count_include_pad (divisor 729), ncc = cov^2/(varI*varJ+eps), out = -mean.
// Shapes fixed: [2,1,192,192,192] fp32.
//
// R12 == R11 resubmitted verbatim (R11 bench never ran: GPU acquisition
// timeout, no counters).
//
// R11: WAVE-PRIVATIZATION. R8-R10 post-mortem: any static-unroll restructure
// spilled rings at the allocator's 128-VGPR pin (WRITE 744-790MB); R7's
// limiter is NOT VALU count but the per-slice block barrier: 4 waves
// lock-step, ~2 blocks/CU -> latency-bound with VALU and LDS both ~44%.
// Fix: wave w produces ITS OWN 16 halo rows (8w..8w+15) into a wave-private
// single LDS buffer and consumes only those:
//  - ZERO barriers in the slice loop (only per-wave lgkmcnt fence between
//    own ds_writes and own ds_reads; same-wave DS ops are pipe-ordered).
//  - 16 rows x 4 quads = 64 x-tasks = one per lane (was 160/256 threads).
//  - single buffer (in-order wave: read slice p, then overwrite with p+1):
//    LDS 22.6 KB; all LDS addresses loop-invariant per thread (no parity).
//  - loop shape stays R7's proven 4x9+tail (no 18/36-deep unroll -> no
//    allocator blow-up). Ring state unchanged (named scalars).
//  - adjacent waves duplicate 24/40 rows of global loads; same block, same
//    time, same XCD-L2 -> HBM FETCH should stay ~116MB compulsory.
// Kept thinnings (verified absmax=0 in R8-R10): rcp EMIT, else-branch LOAD
// zeroing. Carried: 16x32x32 tile, 2 y-outs/thread, XCD swizzle,
// launch_bounds(256,2), xs1 stride 20.

#define S    192
#define SS   (S * S)
#define TX   16
#define YT   32                  // y-tile
#define NTHR 256
#define KZ   32
#define RAD  4
#define WIN  9
#define NSL  (KZ + 2 * RAD)      // 40 slices
#define WROWS 16                 // halo rows per wave (8w .. 8w+15)
#define XSW  17                  // ws4 padded row stride (float4 units)
#define XSW1 20                  // ws1 padded row stride (floats)
#define NVOX (2.0 * S * S * S)

// Per-wave fence: own ds_writes complete before own ds_reads issue.
// NOT a barrier -- waves never rendezvous in the slice loop.
#define LDS_FENCE() __asm__ __volatile__("s_waitcnt lgkmcnt(0)" ::: "memory")

__global__ void ncc_init(double* ws) { ws[0] = 0.0; }

__global__ void ncc_final(const double* __restrict__ ws, float* __restrict__ out) {
    out[0] = (float)(-ws[0] / NVOX);
}

__device__ __forceinline__ float4 f4add(float4 a, float4 b) {
    return make_float4(a.x + b.x, a.y + b.y, a.z + b.z, a.w + b.w);
}
__device__ __forceinline__ float4 f4sub(float4 a, float4 b) {
    return make_float4(a.x - b.x, a.y - b.y, a.z - b.z, a.w - b.w);
}

__global__ __launch_bounds__(NTHR, 2) void ncc_main(const float* __restrict__ I,
                                                    const float* __restrict__ J,
                                                    double* __restrict__ ws) {
    // Wave-private LDS: 4 x 16 rows. ws4 4*16*17*16=17408B, ws1 4*16*20*4=5120B.
    __shared__ float4 ws4[4][WROWS][XSW];   // (sI, sJ, sI2, sJ2)
    __shared__ float  ws1[4][WROWS][XSW1];  // sIJ
    __shared__ float  red[4];

    const int tid  = threadIdx.x;         // 0..255
    const int w    = tid >> 6;            // wave 0..3
    const int lane = tid & 63;
    const int tx   = lane & 15;
    const int tl   = lane >> 4;           // 0..3 -> y-outputs 8w+2tl, +1

    // XCD swizzle over 864 blocks: id&7 = XCD owns a 3x3 xy-patch, bijective.
    const int id  = blockIdx.x;           // 0..863
    const int xcd = id & 7;
    const int lo  = id >> 3;              // 0..107
    const int t   = lo % 9;
    const int bzq = lo / 9;               // 0..11
    const int bx  = (xcd & 3) * 3 + t % 3;     // 0..11
    const int by  = (xcd >> 2) * 3 + t / 3;    // 0..5
    const int b   = (bzq >= 6) ? 1 : 0;
    const int zc  = bzq - 6 * b;
    const int x0 = bx * TX, y0 = by * YT, z0 = zc * KZ;

    const float* Ib = I + (size_t)b * S * SS;
    const float* Jb = J + (size_t)b * S * SS;

    // x-task: EVERY lane. row rloc = lane>>2 (0..15), quad xq = lane&3.
    // Wave w's halo row rloc is global y = y0 - 4 + 8w + rloc.
    const int  rloc = lane >> 2;
    const int  xq   = lane & 3;
    const int  gy   = y0 - RAD + 8 * w + rloc;
    const bool gyv  = ((unsigned)gy < (unsigned)S);
    const int  c0   = x0 + 4 * xq - RAD;
    const bool cv0  = gyv && ((unsigned)(c0    ) < (unsigned)S);
    const bool cv1  = gyv && ((unsigned)(c0 + 4) < (unsigned)S);
    const bool cv2  = gyv && ((unsigned)(c0 + 8) < (unsigned)S);
    const ptrdiff_t rowoff = gyv ? ((ptrdiff_t)gy * S + c0) : 0;

    const float4 F40 = make_float4(0.f, 0.f, 0.f, 0.f);
    // Zero-initialized once: cv-invalid lanes stay 0 forever (cv invariant);
    // z-edge slices re-zero via the else branch (uniform, rare).
    float4 li0 = F40, li1 = F40, li2 = F40, lj0 = F40, lj1 = F40, lj2 = F40;

    auto LOAD = [&](int p) {
        const int zi = z0 - RAD + p;
        if (p < NSL && (unsigned)zi < (unsigned)S) {
            const float* rI = Ib + (size_t)zi * SS + rowoff;
            const float* rJ = Jb + (size_t)zi * SS + rowoff;
            if (cv0) { li0 = *(const float4*)(rI);     lj0 = *(const float4*)(rJ); }
            if (cv1) { li1 = *(const float4*)(rI + 4); lj1 = *(const float4*)(rJ + 4); }
            if (cv2) { li2 = *(const float4*)(rI + 8); lj2 = *(const float4*)(rJ + 8); }
        } else {
            li0 = li1 = li2 = lj0 = lj1 = lj2 = F40;
        }
    };

    // x-phase: every lane, wave-private rows, loop-invariant addresses.
#define XPHASE() do {                                                       \
        const float iv[12] = { li0.x, li0.y, li0.z, li0.w,                  \
                               li1.x, li1.y, li1.z, li1.w,                  \
                               li2.x, li2.y, li2.z, li2.w };                \
        const float jv[12] = { lj0.x, lj0.y, lj0.z, lj0.w,                  \
                               lj1.x, lj1.y, lj1.z, lj1.w,                  \
                               lj2.x, lj2.y, lj2.z, lj2.w };                \
        float a = 0.f, bb = 0.f, c = 0.f, d = 0.f, e = 0.f;                 \
        _Pragma("unroll")                                                   \
        for (int m = 0; m < WIN; ++m) {                                     \
            a += iv[m];                                                     \
            bb += jv[m];                                                    \
            c = fmaf(iv[m], iv[m], c);                                      \
            d = fmaf(jv[m], jv[m], d);                                      \
            e = fmaf(iv[m], jv[m], e);                                      \
        }                                                                   \
        _Pragma("unroll")                                                   \
        for (int k = 0; k < 4; ++k) {                                       \
            if (k > 0) {                                                    \
                a += iv[8 + k] - iv[k - 1];                                 \
                bb += jv[8 + k] - jv[k - 1];                                \
                c += fmaf(iv[8 + k], iv[8 + k], -iv[k - 1] * iv[k - 1]);    \
                d += fmaf(jv[8 + k], jv[8 + k], -jv[k - 1] * jv[k - 1]);    \
                e += fmaf(iv[8 + k], jv[8 + k], -iv[k - 1] * jv[k - 1]);    \
            }                                                               \
            ws4[w][rloc][4 * xq + k] = make_float4(a, bb, c, d);            \
            ws1[w][rloc][4 * xq + k] = e;                                   \
        }                                                                   \
    } while (0)

    // z-rings as NAMED scalars (no arrays -> no scratch demotion possible).
    float4 a4_0 = F40, a4_1 = F40, a4_2 = F40, a4_3 = F40, a4_4 = F40,
           a4_5 = F40, a4_6 = F40, a4_7 = F40, a4_8 = F40;
    float  a1_0 = 0.f, a1_1 = 0.f, a1_2 = 0.f, a1_3 = 0.f, a1_4 = 0.f,
           a1_5 = 0.f, a1_6 = 0.f, a1_7 = 0.f, a1_8 = 0.f;
    float4 b4_0 = F40, b4_1 = F40, b4_2 = F40, b4_3 = F40, b4_4 = F40,
           b4_5 = F40, b4_6 = F40, b4_7 = F40, b4_8 = F40;
    float  b1_0 = 0.f, b1_1 = 0.f, b1_2 = 0.f, b1_3 = 0.f, b1_4 = 0.f,
           b1_5 = 0.f, b1_6 = 0.f, b1_7 = 0.f, b1_8 = 0.f;
    float4 runA4 = F40, runB4 = F40;
    float  runA1 = 0.f, runB1 = 0.f;
    float  acc = 0.f;
    const int yA = 2 * tl;                // wave-local rows yA..yA+9 (<= 15)

    // One-instruction reciprocal (v_rcp_f32, ~1 ulp): final |err| ~1e-10 abs.
#define EMIT(R4, R1) do {                                                   \
        const float inv_ = 1.0f / 729.0f;                                   \
        const float mI_ = (R4).x * inv_, mJ_ = (R4).y * inv_;               \
        const float vI_ = (R4).z * inv_ - mI_ * mI_;                        \
        const float vJ_ = (R4).w * inv_ - mJ_ * mJ_;                        \
        const float cIJ_ = (R1) * inv_ - mI_ * mJ_;                         \
        acc = fmaf(cIJ_ * cIJ_,                                             \
                   __builtin_amdgcn_rcpf(vI_ * vJ_ + 1e-5f), acc);          \
    } while (0)

    // y-phase: R7's proven sequential form, wave-private rows, static K.
#define YSTEP(K, DOEMIT) do {                                               \
        const float4 t0_4 = ws4[w][yA][tx];                                 \
        const float  t0_1 = ws1[w][yA][tx];                                 \
        float4 s4 = t0_4;                                                   \
        float  s1 = t0_1;                                                   \
        _Pragma("unroll")                                                   \
        for (int j_ = 1; j_ < WIN; ++j_) {                                  \
            s4 = f4add(s4, ws4[w][yA + j_][tx]);                            \
            s1 += ws1[w][yA + j_][tx];                                      \
        }                                                                   \
        const float4 t9_4 = ws4[w][yA + WIN][tx];                           \
        const float  t9_1 = ws1[w][yA + WIN][tx];                           \
        const float4 sB4 = f4add(f4sub(s4, t0_4), t9_4);                    \
        const float  sB1 = s1 - t0_1 + t9_1;                                \
        runA4 = f4add(runA4, f4sub(s4, a4_##K));   a4_##K = s4;             \
        runA1 += s1 - a1_##K;                      a1_##K = s1;             \
        runB4 = f4add(runB4, f4sub(sB4, b4_##K));  b4_##K = sB4;            \
        runB1 += sB1 - b1_##K;                     b1_##K = sB1;            \
        if (DOEMIT) { EMIT(runA4, runA1); EMIT(runB4, runB1); }             \
    } while (0)

    // Per-wave slice p: x-write(p) | prefetch(p+1) | own-write fence | y(p).
    // No s_barrier: wave w touches only ws4[w]/ws1[w].
#define BODY(K, DOEMIT) do {                                                \
        XPHASE();                                                           \
        LOAD(idx + 1);                                                      \
        LDS_FENCE();                                                        \
        YSTEP(K, DOEMIT);                                                   \
        ++idx;                                                              \
    } while (0)

    LOAD(0);

    // 4 groups of 9 (p = 9g..9g+8, K = p%9 static). Emit from p >= 8:
    // group 0 positions 0..7 static-false, position 8 static-true; groups
    // 1..3 all true via uniform em.
    int idx = 0;
    #pragma unroll 1
    for (int g = 0; g < 4; ++g) {
        const bool em = (g != 0);
        BODY(0, em); BODY(1, em); BODY(2, em); BODY(3, em); BODY(4, em);
        BODY(5, em); BODY(6, em); BODY(7, em); BODY(8, true);
    }
    // Tail: p = 36, 37, 38 (K 0,1,2), then final y-only slice p = 39 (K 3).
    BODY(0, true);
    BODY(1, true);
    BODY(2, true);
    XPHASE();
    LDS_FENCE();
    YSTEP(3, true);
#undef BODY
#undef YSTEP
#undef EMIT
#undef XPHASE

    // Block reduction: wave shuffle -> LDS -> one double atomic.
    // (__syncthreads here is the ONLY block-wide sync; once per block.)
    float v = acc;
    #pragma unroll
    for (int off = 32; off >= 1; off >>= 1)
        v += __shfl_down(v, off, 64);
    const int wid = tid >> 6;
    if (lane == 0) red[wid] = v;
    __syncthreads();
    if (tid == 0) {
        atomicAdd(ws, (double)(red[0] + red[1] + red[2] + red[3]));
    }
}

extern "C" void kernel_launch(void* const* d_in, const int* in_sizes, int n_in,
                              void* d_out, int out_size, void* d_ws, size_t ws_size,
                              hipStream_t stream) {
    const float* I = (const float*)d_in[0];   // y_pred
    const float* J = (const float*)d_in[1];   // y_true
    double* ws = (double*)d_ws;
    float* out = (float*)d_out;

    hipLaunchKernelGGL(ncc_init, dim3(1), dim3(1), 0, stream, ws);

    hipLaunchKernelGGL(ncc_main, dim3(12 * 6 * 12), dim3(NTHR), 0, stream,
                       I, J, ws);

    hipLaunchKernelGGL(ncc_final, dim3(1), dim3(1), 0, stream, ws, out);
}